// Round 3
// baseline (14834.148 us; speedup 1.0000x reference)
//
#include <hip/hip_runtime.h>

// Deep Kalman Filter inference, MI355X/gfx950.
// Phases: pack (weights -> fp16 MFMA A-fragments), fused single-WG scan
// (16 WG x 1024 thr; ALL weights register-resident; LDS-only exchange),
// parallel transition/emitter/loss (2048 WG), finalize.

#define T_LEN 512
#define BATCH 256
#define DIMX  128
#define ZDIM  128
#define RHD   512

typedef _Float16 f16;
typedef _Float16 f16x2 __attribute__((ext_vector_type(2)));
typedef _Float16 f16x4 __attribute__((ext_vector_type(4)));
typedef _Float16 f16x8 __attribute__((ext_vector_type(8)));
typedef float    f32x4 __attribute__((ext_vector_type(4)));

#define MFMA16(a,b,c) __builtin_amdgcn_mfma_f32_16x16x32_f16((a),(b),(c),0,0,0)

// ---- packed weight element offsets (f16 elements) ----
#define PK_WIH  0u
#define PK_WHH  65536u
#define PK_G1   327680u
#define PK_G2   360448u
#define PK_P1   393216u
#define PK_P2   425984u
#define PK_TMU  458752u
#define PK_TLV  475136u
#define PK_CBH  491520u
#define PK_CBML 557056u
#define PK_E1   688128u
#define PK_E2   720896u
#define PK_EMU  786432u

// ---- workspace byte offsets ----
#define WS_Z    0ull                          // f16 [T+1][B][Z]
#define WS_MU   (WS_Z   + 33619968ull)        // f16 [T][B][Z]
#define WS_LV   (WS_MU  + 33554432ull)        // f16 [T][B][Z]
#define WS_PK   (WS_LV  + 33554432ull)        // f16 packed weights
#define WS_PART (WS_PK  + 1638400ull)         // f32 [2048][2]
#define WS_END  (WS_PART + 16384ull)

// =====================================================================
// helpers
// =====================================================================
__device__ __forceinline__ void ldsfence() {
  asm volatile("s_waitcnt lgkmcnt(0)" ::: "memory");
  __builtin_amdgcn_sched_barrier(0);
}

template<int N>
__device__ __forceinline__ void zacc(f32x4* a) {
  f32x4 z = {0.f, 0.f, 0.f, 0.f};
#pragma unroll
  for (int i = 0; i < N; ++i) a[i] = z;
}

__device__ __forceinline__ f16x8 cvt8(const float* p) {
  float4 a = *(const float4*)p, b = *(const float4*)(p + 4);
  f16x8 r;
  r[0] = (f16)a.x; r[1] = (f16)a.y; r[2] = (f16)a.z; r[3] = (f16)a.w;
  r[4] = (f16)b.x; r[5] = (f16)b.y; r[6] = (f16)b.z; r[7] = (f16)b.w;
  return r;
}

// A-frag load from LDS tile [16][stride] (row = lane&15). (dpar)
template<int KS>
__device__ __forceinline__ void load_af(const f16* src, int sstr, int lane, f16x8* af) {
#pragma unroll
  for (int ks = 0; ks < KS; ++ks)
    af[ks] = *(const f16x8*)(src + (lane & 15) * sstr + ks * 32 + ((lane >> 4) << 3));
}

template<int KS, int NT>
__device__ __forceinline__ void gemm_regA(const f16x8* af, const f16* __restrict__ bp,
                                          int lane, f32x4* acc) {
#pragma unroll
  for (int ks = 0; ks < KS; ++ks)
#pragma unroll
    for (int j = 0; j < NT; ++j) {
      f16x8 bf = *(const f16x8*)(bp + (((size_t)(ks * NT + j)) << 9) + (lane << 3));
      acc[j] = MFMA16(af[ks], bf, acc[j]);
    }
}

template<int NT>
__device__ __forceinline__ void store_relu(const f32x4* acc, const float* __restrict__ bias,
                                           f16* dst, int dstr, int lane) {
  int colv = lane & 15, rb = (lane >> 4) << 2;
#pragma unroll
  for (int j = 0; j < NT; ++j)
#pragma unroll
    for (int r = 0; r < 4; ++r)
      dst[(rb + r) * dstr + j * 16 + colv] = (f16)fmaxf(acc[j][r] + bias[j * 16 + colv], 0.f);
}

// =====================================================================
// pack: W[K][N] fp32 -> fp16 fragments (frag fi = ks*(N/16) + nt).
// element (k,n): k = ks*32 + (l>>4)*8 + j, n = nt*16 + (l&15)
// =====================================================================
__global__ void pack_kernel(const float* __restrict__ s1, const float* __restrict__ s2,
                            int nsplit, int K, int N, f16* __restrict__ dst) {
  int idx = blockIdx.x * 256 + threadIdx.x;
  if (idx >= K * N) return;
  int j = idx & 7, l = (idx >> 3) & 63, fi = idx >> 9;
  int NTt = N >> 4;
  int nt = fi % NTt, ks = fi / NTt;
  int k = ks * 32 + ((l >> 4) << 3) + j;
  int n = (nt << 4) + (l & 15);
  float v;
  if (n < nsplit) v = s1[(size_t)k * nsplit + n];
  else            v = s2[(size_t)k * (N - nsplit) + (n - nsplit)];
  dst[idx] = (f16)v;
}

// =====================================================================
// Fused scan: 16 WGs x 1024 threads (16 waves). WG owns 16 batch rows.
// Wave (m = w&7, k = w>>3): 2D grid, 8 M-groups x 2 K-halves.
//  P0+P1: acc_h[4 Mtiles rows 64m..+64] = Wih@x(K-half) + Whh@h(K-half)
//  P2:    acc_c[4 Mtiles]               = cbh@z(K-half)
//  pair-exchange with wave w^8 (f16 partials via LDS), in-reg epilogue:
//  h = relu(.), hc = 0.5*(tanh(.)+h) -> h_st/hc_st
//  P3:    acc_m[2 Mtiles of 256]        = cbml@hc(K-half) -> m_part[k]
//  z-epilogue: z = mu + eps*exp(0.5 lv) -> z_st + global z/mu/lv.
// All weights live in registers as A-frags (256 VGPR/lane).
// =====================================================================
__global__ __launch_bounds__(1024) void scan_kernel(
    const float* __restrict__ x, const f16* __restrict__ pk,
    const float* __restrict__ bih, const float* __restrict__ bhh,
    const float* __restrict__ h0, const float* __restrict__ zq0,
    const float* __restrict__ chb, const float* __restrict__ cmb,
    const float* __restrict__ clb, const float* __restrict__ eps_comb,
    f16* __restrict__ z_all, f16* __restrict__ mu_all, f16* __restrict__ lv_all) {
  __shared__ __align__(16) f16 h_st[16][520];
  __shared__ __align__(16) f16 hc_st[16][520];
  __shared__ __align__(16) f16 m_part[2][16][264];
  __shared__ __align__(16) f16 z_st[16][136];
  __shared__ __align__(16) f16 pair_h[32][16][20];  // [w*2+slot][colv][16 rows + pad]
  __shared__ __align__(16) f16 pair_c[32][16][20];

  const int tid = threadIdx.x, lane = tid & 63, w = tid >> 6;
  const int m = w & 7, k = w >> 3;
  const int colv = lane & 15, l4 = lane >> 4;
  const int b0 = blockIdx.x * 16;

  // ---- t-invariant weight A-frags in registers ----
  f16x8 whhA[4][8], wihA[4][2], cbhA[4][2], cbmlA[2][8];
#pragma unroll
  for (int mt = 0; mt < 4; ++mt) {
#pragma unroll
    for (int ks = 0; ks < 8; ++ks)
      whhA[mt][ks] = *(const f16x8*)(pk + PK_WHH +
          ((size_t)((8 * k + ks) * 32 + (4 * m + mt)) << 9) + (lane << 3));
#pragma unroll
    for (int ks = 0; ks < 2; ++ks) {
      wihA[mt][ks] = *(const f16x8*)(pk + PK_WIH +
          ((size_t)((2 * k + ks) * 32 + (4 * m + mt)) << 9) + (lane << 3));
      cbhA[mt][ks] = *(const f16x8*)(pk + PK_CBH +
          ((size_t)((2 * k + ks) * 32 + (4 * m + mt)) << 9) + (lane << 3));
    }
  }
#pragma unroll
  for (int mt = 0; mt < 2; ++mt)
#pragma unroll
    for (int ks = 0; ks < 8; ++ks)
      cbmlA[mt][ks] = *(const f16x8*)(pk + PK_CBML +
          ((size_t)((8 * k + ks) * 16 + (2 * m + mt)) << 9) + (lane << 3));

  // epilogue bias constants for the 2 owned M-tiles (rows (4m+2k+s)*16+l4*4+r)
  float bsum[2][4], chbv[2][4];
#pragma unroll
  for (int s = 0; s < 2; ++s)
#pragma unroll
    for (int r = 0; r < 4; ++r) {
      int d = (4 * m + 2 * k + s) * 16 + l4 * 4 + r;
      bsum[s][r] = bih[d] + bhh[d];
      chbv[s][r] = chb[d];
    }
  // z-epilogue mapping: thread -> (batch be, dims d0,d0+1)
  const int be = tid >> 6, d0 = (tid & 63) * 2;
  const float cmb0 = cmb[d0], cmb1 = cmb[d0 + 1];
  const float clb0 = clb[d0], clb1 = clb[d0 + 1];

  // ---- init h_st = h0 (broadcast), z_st = zq0; write z_all[0] ----
  for (int i = tid; i < 16 * RHD; i += 1024) h_st[i >> 9][i & 511] = (f16)h0[i & 511];
  for (int i = tid; i < 16 * ZDIM; i += 1024) {
    f16 zv = (f16)zq0[i & 127];
    z_st[i >> 7][i & 127] = zv;
    z_all[(size_t)(b0 + (i >> 7)) * ZDIM + (i & 127)] = zv;
  }
  __syncthreads();

  const float* xrow = x + (size_t)(b0 + colv) * (T_LEN * DIMX);

#pragma unroll 1
  for (int t = 0; t < T_LEN; ++t) {
    // ---- ph1: B-frag reads (K-half) + global prefetch ----
    f16x8 B8[8], zB[2], xB[2];
#pragma unroll
    for (int ks = 0; ks < 2; ++ks)
      xB[ks] = cvt8(xrow + t * DIMX + (2 * k + ks) * 32 + l4 * 8);
    float2 ep = *(const float2*)(eps_comb + ((size_t)t * BATCH + b0 + be) * ZDIM + d0);
#pragma unroll
    for (int ks = 0; ks < 8; ++ks)
      B8[ks] = *(const f16x8*)&h_st[colv][(8 * k + ks) * 32 + l4 * 8];
#pragma unroll
    for (int ks = 0; ks < 2; ++ks)
      zB[ks] = *(const f16x8*)&z_st[colv][(2 * k + ks) * 32 + l4 * 8];

    // ---- ph2: MFMAs ----
    f32x4 ah[4], ac[4];
    zacc<4>(ah); zacc<4>(ac);
#pragma unroll
    for (int ks = 0; ks < 8; ++ks)
#pragma unroll
      for (int mt = 0; mt < 4; ++mt)
        ah[mt] = MFMA16(whhA[mt][ks], B8[ks], ah[mt]);
#pragma unroll
    for (int ks = 0; ks < 2; ++ks)
#pragma unroll
      for (int mt = 0; mt < 4; ++mt) {
        ah[mt] = MFMA16(wihA[mt][ks], xB[ks], ah[mt]);
        ac[mt] = MFMA16(cbhA[mt][ks], zB[ks], ac[mt]);
      }

    // ---- ph3: write non-owned partial tiles (wave-uniform branch) ----
#define PAIRW(MT, S)                                                        \
    {                                                                       \
      f16x4 vh, vc;                                                         \
      _Pragma("unroll")                                                     \
      for (int r = 0; r < 4; ++r) { vh[r] = (f16)ah[MT][r]; vc[r] = (f16)ac[MT][r]; } \
      *(f16x4*)&pair_h[w * 2 + (S)][colv][l4 * 4] = vh;                     \
      *(f16x4*)&pair_c[w * 2 + (S)][colv][l4 * 4] = vc;                     \
    }
    if (k == 0) { PAIRW(2, 0) PAIRW(3, 1) } else { PAIRW(0, 0) PAIRW(1, 1) }
#undef PAIRW
    __syncthreads();  // B1

    // ---- ph4: epilogue for owned tiles (read partner partial, finalize) ----
#define EPI(MT, S)                                                          \
    {                                                                       \
      f16x4 hp = *(const f16x4*)&pair_h[(w ^ 8) * 2 + (S)][colv][l4 * 4];   \
      f16x4 cp = *(const f16x4*)&pair_c[(w ^ 8) * 2 + (S)][colv][l4 * 4];   \
      f16x4 h4, hc4;                                                        \
      _Pragma("unroll")                                                     \
      for (int r = 0; r < 4; ++r) {                                         \
        float hv = fmaxf(ah[MT][r] + (float)hp[r] + bsum[S][r], 0.f);       \
        float cs = ac[MT][r] + (float)cp[r] + chbv[S][r];                   \
        float tt = __builtin_amdgcn_exp2f(cs * 2.885390082f);               \
        float th = 1.f - 2.f * __builtin_amdgcn_rcpf(tt + 1.f);             \
        h4[r] = (f16)hv;                                                    \
        hc4[r] = (f16)(0.5f * (th + hv));                                   \
      }                                                                     \
      int dd = (4 * m + 2 * k + (S)) * 16 + l4 * 4;                         \
      *(f16x4*)&h_st[colv][dd] = h4;                                        \
      *(f16x4*)&hc_st[colv][dd] = hc4;                                      \
    }
    if (k == 0) { EPI(0, 0) EPI(1, 1) } else { EPI(2, 0) EPI(3, 1) }
#undef EPI
    __syncthreads();  // B2

    // ---- ph5: P3 mu|lv partial (reuse B8 for hc) ----
#pragma unroll
    for (int ks = 0; ks < 8; ++ks)
      B8[ks] = *(const f16x8*)&hc_st[colv][(8 * k + ks) * 32 + l4 * 8];
    f32x4 am[2];
    zacc<2>(am);
#pragma unroll
    for (int ks = 0; ks < 8; ++ks)
#pragma unroll
      for (int mt = 0; mt < 2; ++mt)
        am[mt] = MFMA16(cbmlA[mt][ks], B8[ks], am[mt]);
#pragma unroll
    for (int mt = 0; mt < 2; ++mt) {
      f16x4 v;
#pragma unroll
      for (int r = 0; r < 4; ++r) v[r] = (f16)am[mt][r];
      *(f16x4*)&m_part[k][colv][(2 * m + mt) * 16 + l4 * 4] = v;
    }
    __syncthreads();  // B3

    // ---- ph6: z epilogue (thread -> batch be, dims d0..d0+1) ----
    {
      f16x2 mua = *(const f16x2*)&m_part[0][be][d0];
      f16x2 mub = *(const f16x2*)&m_part[1][be][d0];
      f16x2 lva = *(const f16x2*)&m_part[0][be][128 + d0];
      f16x2 lvb = *(const f16x2*)&m_part[1][be][128 + d0];
      float mu0 = (float)mua[0] + (float)mub[0] + cmb0;
      float mu1 = (float)mua[1] + (float)mub[1] + cmb1;
      float lv0 = (float)lva[0] + (float)lvb[0] + clb0;
      float lv1 = (float)lva[1] + (float)lvb[1] + clb1;
      float z0 = mu0 + ep.x * __builtin_amdgcn_exp2f(lv0 * 0.7213475204f);
      float z1 = mu1 + ep.y * __builtin_amdgcn_exp2f(lv1 * 0.7213475204f);
      f16x2 z2; z2[0] = (f16)z0; z2[1] = (f16)z1;
      f16x2 mu2; mu2[0] = (f16)mu0; mu2[1] = (f16)mu1;
      f16x2 lv2; lv2[0] = (f16)lv0; lv2[1] = (f16)lv1;
      *(f16x2*)&z_st[be][d0] = z2;
      size_t o = ((size_t)t * BATCH + b0 + be) * ZDIM + d0;
      *(f16x2*)(mu_all + o) = mu2;
      *(f16x2*)(lv_all + o) = lv2;
      *(f16x2*)(z_all + o + (size_t)BATCH * ZDIM) = z2;  // slot t+1
    }
    __syncthreads();  // B4
  }
}

// =====================================================================
// Phase D: parallel transition/emitter/losses over all (t,b). (unchanged)
// =====================================================================
__global__ __launch_bounds__(256) void dpar_kernel(
    const f16* __restrict__ z_all, const f16* __restrict__ mu_all,
    const f16* __restrict__ lv_all, const float* __restrict__ y,
    const float* __restrict__ eps_emit, const f16* __restrict__ pk,
    const float* __restrict__ g1b, const float* __restrict__ g2b,
    const float* __restrict__ p1b, const float* __restrict__ p2b,
    const float* __restrict__ tmub, const float* __restrict__ tlvb,
    const float* __restrict__ e1b, const float* __restrict__ e2b,
    const float* __restrict__ emub, const float* __restrict__ em_logvar,
    float* __restrict__ partials) {
  __shared__ __align__(16) f16 sb256[4][16 * 264];
  __shared__ __align__(16) f16 sb128[4][16 * 136];
  __shared__ float wsum[4][2];
  const int tid = threadIdx.x, lane = tid & 63, w = tid >> 6;
  const int colv = lane & 15, rb = (lane >> 4) << 2;
  const int m0 = blockIdx.x * 64 + w * 16;
  const int t = m0 >> 8, b0 = m0 & 255;
  f16* B256 = &sb256[w][0];
  f16* B128 = &sb128[w][0];

  f16x8 zp[4], zt[4];
  const f16* zpr = z_all + ((size_t)t * BATCH + b0) * ZDIM;
#pragma unroll
  for (int ks = 0; ks < 4; ++ks) {
    zp[ks] = *(const f16x8*)(zpr + (size_t)colv * ZDIM + ks * 32 + ((lane >> 4) << 3));
    zt[ks] = *(const f16x8*)(zpr + (size_t)BATCH * ZDIM + (size_t)colv * ZDIM + ks * 32 + ((lane >> 4) << 3));
  }

  f32x4 a16[16], a8[8];
  f16x8 af[8], af4[4];
  zacc<16>(a16); gemm_regA<4, 16>(zp, pk + PK_G1, lane, a16);
  store_relu<16>(a16, g1b, B256, 264, lane); ldsfence();
  load_af<8>(B256, 264, lane, af); ldsfence();
  zacc<8>(a8); gemm_regA<8, 8>(af, pk + PK_G2, lane, a8);
  f32x4 gate[8];
#pragma unroll
  for (int j = 0; j < 8; ++j)
#pragma unroll
    for (int r = 0; r < 4; ++r)
      gate[j][r] = 1.f / (1.f + expf(-(a8[j][r] + g2b[j * 16 + colv])));
  zacc<16>(a16); gemm_regA<4, 16>(zp, pk + PK_P1, lane, a16);
  store_relu<16>(a16, p1b, B256, 264, lane); ldsfence();
  load_af<8>(B256, 264, lane, af); ldsfence();
  zacc<8>(a8); gemm_regA<8, 8>(af, pk + PK_P2, lane, a8);
  f32x4 prop[8];
#pragma unroll
  for (int j = 0; j < 8; ++j)
#pragma unroll
    for (int r = 0; r < 4; ++r) {
      float v = a8[j][r] + p2b[j * 16 + colv];
      prop[j][r] = v;
      B128[(rb + r) * 136 + j * 16 + colv] = (f16)fmaxf(v, 0.f);
    }
  ldsfence();
  zacc<8>(a8); gemm_regA<4, 8>(zp, pk + PK_TMU, lane, a8);
  f32x4 prmu[8];
#pragma unroll
  for (int j = 0; j < 8; ++j)
#pragma unroll
    for (int r = 0; r < 4; ++r) {
      float gg = gate[j][r];
      prmu[j][r] = (1.f - gg) * (a8[j][r] + tmub[j * 16 + colv]) + gg * prop[j][r];
    }
  load_af<4>(B128, 136, lane, af4); ldsfence();
  zacc<8>(a8); gemm_regA<4, 8>(af4, pk + PK_TLV, lane, a8);
  f32x4 prlv[8];
#pragma unroll
  for (int j = 0; j < 8; ++j)
#pragma unroll
    for (int r = 0; r < 4; ++r) prlv[j][r] = a8[j][r] + tlvb[j * 16 + colv];
  zacc<16>(a16); gemm_regA<4, 16>(zt, pk + PK_E1, lane, a16);
  store_relu<16>(a16, e1b, B256, 264, lane); ldsfence();
  load_af<8>(B256, 264, lane, af); ldsfence();
  zacc<16>(a16); gemm_regA<8, 16>(af, pk + PK_E2, lane, a16);
  store_relu<16>(a16, e2b, B256, 264, lane); ldsfence();
  load_af<8>(B256, 264, lane, af); ldsfence();
  zacc<8>(a8); gemm_regA<8, 8>(af, pk + PK_EMU, lane, a8);
  float srec = 0.f, skl = 0.f;
#pragma unroll
  for (int j = 0; j < 8; ++j)
#pragma unroll
    for (int r = 0; r < 4; ++r) {
      int row = rb + r, n = j * 16 + colv;
      size_t tb = (size_t)t * BATCH + b0 + row;
      float xt = a8[j][r] + emub[n] + eps_emit[tb * DIMX + n] * expf(0.5f * em_logvar[n]);
      float dy = xt - y[((size_t)(b0 + row) * T_LEN + t) * DIMX + n];
      srec += dy * dy;
      float m_ = (float)mu_all[tb * ZDIM + n], l_ = (float)lv_all[tb * ZDIM + n];
      float dm = m_ - prmu[j][r];
      skl += 0.5f * (prlv[j][r] - l_ + (expf(l_) + dm * dm) * expf(-prlv[j][r]) - 1.f);
    }
#pragma unroll
  for (int off = 32; off; off >>= 1) {
    srec += __shfl_xor(srec, off);
    skl += __shfl_xor(skl, off);
  }
  if (lane == 0) { wsum[w][0] = srec; wsum[w][1] = skl; }
  __syncthreads();
  if (tid == 0) {
    partials[blockIdx.x * 2 + 0] = wsum[0][0] + wsum[1][0] + wsum[2][0] + wsum[3][0];
    partials[blockIdx.x * 2 + 1] = wsum[0][1] + wsum[1][1] + wsum[2][1] + wsum[3][1];
  }
}

// =====================================================================
__global__ void finalize_kernel(const float* __restrict__ partials, float* __restrict__ out) {
  __shared__ float sm[256][2];
  int tid = threadIdx.x;
  float r = 0.f, kk = 0.f;
  for (int i = tid; i < 2048; i += 256) {
    r += partials[2 * i];
    kk += partials[2 * i + 1];
  }
  sm[tid][0] = r; sm[tid][1] = kk;
  __syncthreads();
  for (int off = 128; off; off >>= 1) {
    if (tid < off) { sm[tid][0] += sm[tid + off][0]; sm[tid][1] += sm[tid + off][1]; }
    __syncthreads();
  }
  if (tid == 0) {
    out[0] = sm[0][0] / (131072.f * 128.f);
    out[1] = sm[0][1] / 131072.f;
  }
}

// =====================================================================
extern "C" void kernel_launch(void* const* d_in, const int* in_sizes, int n_in,
                              void* d_out, int out_size, void* d_ws, size_t ws_size,
                              hipStream_t stream) {
  (void)in_sizes; (void)n_in; (void)out_size;
  const float* x        = (const float*)d_in[0];
  const float* y        = (const float*)d_in[1];
  const float* eps_comb = (const float*)d_in[2];
  const float* eps_emit = (const float*)d_in[3];
  const float* wih = (const float*)d_in[4];
  const float* whh = (const float*)d_in[5];
  const float* bih = (const float*)d_in[6];
  const float* bhh = (const float*)d_in[7];
  const float* h0  = (const float*)d_in[8];
  const float* zq0 = (const float*)d_in[9];
  const float* g1W = (const float*)d_in[10]; const float* g1b = (const float*)d_in[11];
  const float* g2W = (const float*)d_in[12]; const float* g2b = (const float*)d_in[13];
  const float* p1W = (const float*)d_in[14]; const float* p1b = (const float*)d_in[15];
  const float* p2W = (const float*)d_in[16]; const float* p2b = (const float*)d_in[17];
  const float* tmuW = (const float*)d_in[18]; const float* tmub = (const float*)d_in[19];
  const float* tlvW = (const float*)d_in[20]; const float* tlvb = (const float*)d_in[21];
  const float* chW = (const float*)d_in[22]; const float* chb = (const float*)d_in[23];
  const float* cmW = (const float*)d_in[24]; const float* cmb = (const float*)d_in[25];
  const float* clW = (const float*)d_in[26]; const float* clb = (const float*)d_in[27];
  const float* e1W = (const float*)d_in[28]; const float* e1b = (const float*)d_in[29];
  const float* e2W = (const float*)d_in[30]; const float* e2b = (const float*)d_in[31];
  const float* emW = (const float*)d_in[32]; const float* emb = (const float*)d_in[33];
  const float* elv = (const float*)d_in[34];

  char* ws = (char*)d_ws;
  f16*  z_all   = (f16*)(ws + WS_Z);
  f16*  mu_all  = (f16*)(ws + WS_MU);
  f16*  lv_all  = (f16*)(ws + WS_LV);
  f16*  pk      = (f16*)(ws + WS_PK);
  float* partials = (float*)(ws + WS_PART);
  float* out = (float*)d_out;
  if (ws_size < WS_END) return;

#define PACK(S1, S2, NS_, K, N, OFF) \
  pack_kernel<<<dim3(((K) * (N)) / 256), dim3(256), 0, stream>>>(S1, S2, NS_, K, N, pk + (OFF))
  PACK(wih, wih, 512, 128, 512, PK_WIH);
  PACK(whh, whh, 512, 512, 512, PK_WHH);
  PACK(g1W, g1W, 256, 128, 256, PK_G1);
  PACK(g2W, g2W, 128, 256, 128, PK_G2);
  PACK(p1W, p1W, 256, 128, 256, PK_P1);
  PACK(p2W, p2W, 128, 256, 128, PK_P2);
  PACK(tmuW, tmuW, 128, 128, 128, PK_TMU);
  PACK(tlvW, tlvW, 128, 128, 128, PK_TLV);
  PACK(chW, chW, 512, 128, 512, PK_CBH);
  PACK(cmW, clW, 128, 512, 256, PK_CBML);
  PACK(e1W, e1W, 256, 128, 256, PK_E1);
  PACK(e2W, e2W, 256, 256, 256, PK_E2);
  PACK(emW, emW, 128, 256, 128, PK_EMU);
#undef PACK

  scan_kernel<<<dim3(16), dim3(1024), 0, stream>>>(
      x, pk, bih, bhh, h0, zq0, chb, cmb, clb, eps_comb, z_all, mu_all, lv_all);
  dpar_kernel<<<dim3(2048), dim3(256), 0, stream>>>(z_all, mu_all, lv_all, y, eps_emit, pk,
                                                    g1b, g2b, p1b, p2b, tmub, tlvb, e1b, e2b,
                                                    emb, elv, partials);
  finalize_kernel<<<dim3(1), dim3(256), 0, stream>>>(partials, out);
}

// Round 4
// 3341.114 us; speedup vs baseline: 4.4399x; 4.4399x over previous
//
#include <hip/hip_runtime.h>

// Deep Kalman Filter inference, MI355X/gfx950.
// Phases: pack (weights -> fp16 MFMA fragments), xw = x@Wih+bias (parallel),
// rnn scan (16 WG, Whh fully on-chip: 192 VGPR + 128KB LDS),
// z scan (16 WG, cbh LDS + cbml regs), transition/emitter/loss (2048 WG),
// finalize. No cross-WG sync anywhere (R2 lesson: agent-scope sync ~6.6us).

#define T_LEN 512
#define BATCH 256
#define DIMX  128
#define ZDIM  128
#define RHD   512

typedef _Float16 f16;
typedef _Float16 f16x4 __attribute__((ext_vector_type(4)));
typedef _Float16 f16x8 __attribute__((ext_vector_type(8)));
typedef float    f32x4 __attribute__((ext_vector_type(4)));

#define MFMA16(a,b,c) __builtin_amdgcn_mfma_f32_16x16x32_f16((a),(b),(c),0,0,0)

// ---- packed weight element offsets (f16 elements) ----
#define PK_WIH  0u
#define PK_WHH  65536u
#define PK_G1   327680u
#define PK_G2   360448u
#define PK_P1   393216u
#define PK_P2   425984u
#define PK_TMU  458752u
#define PK_TLV  475136u
#define PK_CBH  491520u
#define PK_CBML 557056u
#define PK_E1   688128u
#define PK_E2   720896u
#define PK_EMU  786432u

// ---- workspace byte offsets ----
#define WS_XW   0ull                          // f16 [T][B][RH]: xw in, h out (aliased)
#define WS_Z    (WS_XW  + 134217728ull)       // f16 [T+1][B][Z]
#define WS_MU   (WS_Z   + 33619968ull)        // f16 [T][B][Z]
#define WS_LV   (WS_MU  + 33554432ull)        // f16 [T][B][Z]
#define WS_PK   (WS_LV  + 33554432ull)        // f16 packed weights
#define WS_PART (WS_PK  + 1638400ull)         // f32 [2048][2]
#define WS_END  (WS_PART + 16384ull)

// =====================================================================
// helpers
// =====================================================================
__device__ __forceinline__ void ldsfence() {
  asm volatile("s_waitcnt lgkmcnt(0)" ::: "memory");
  __builtin_amdgcn_sched_barrier(0);
}

template<int N>
__device__ __forceinline__ void zacc(f32x4* a) {
  f32x4 z = {0.f, 0.f, 0.f, 0.f};
#pragma unroll
  for (int i = 0; i < N; ++i) a[i] = z;
}

__device__ __forceinline__ f16x8 cvt8(const float* p) {
  float4 a = *(const float4*)p, b = *(const float4*)(p + 4);
  f16x8 r;
  r[0] = (f16)a.x; r[1] = (f16)a.y; r[2] = (f16)a.z; r[3] = (f16)a.w;
  r[4] = (f16)b.x; r[5] = (f16)b.y; r[6] = (f16)b.z; r[7] = (f16)b.w;
  return r;
}

// A-frag load from LDS tile [16][stride] (row = lane&15). (dpar)
template<int KS>
__device__ __forceinline__ void load_af(const f16* src, int sstr, int lane, f16x8* af) {
#pragma unroll
  for (int ks = 0; ks < KS; ++ks)
    af[ks] = *(const f16x8*)(src + (lane & 15) * sstr + ks * 32 + ((lane >> 4) << 3));
}

template<int KS, int NT>
__device__ __forceinline__ void gemm_regA(const f16x8* af, const f16* __restrict__ bp,
                                          int lane, f32x4* acc) {
#pragma unroll
  for (int ks = 0; ks < KS; ++ks)
#pragma unroll
    for (int j = 0; j < NT; ++j) {
      f16x8 bf = *(const f16x8*)(bp + (((size_t)(ks * NT + j)) << 9) + (lane << 3));
      acc[j] = MFMA16(af[ks], bf, acc[j]);
    }
}

template<int NT>
__device__ __forceinline__ void store_relu(const f32x4* acc, const float* __restrict__ bias,
                                           f16* dst, int dstr, int lane) {
  int colv = lane & 15, rb = (lane >> 4) << 2;
#pragma unroll
  for (int j = 0; j < NT; ++j)
#pragma unroll
    for (int r = 0; r < 4; ++r)
      dst[(rb + r) * dstr + j * 16 + colv] = (f16)fmaxf(acc[j][r] + bias[j * 16 + colv], 0.f);
}

// =====================================================================
// pack: W[K][N] fp32 -> fp16 fragments (frag fi = ks*(N/16) + nt).
// element (k,n): k = ks*32 + (l>>4)*8 + j, n = nt*16 + (l&15)
// =====================================================================
__global__ void pack_kernel(const float* __restrict__ s1, const float* __restrict__ s2,
                            int nsplit, int K, int N, f16* __restrict__ dst) {
  int idx = blockIdx.x * 256 + threadIdx.x;
  if (idx >= K * N) return;
  int j = idx & 7, l = (idx >> 3) & 63, fi = idx >> 9;
  int NTt = N >> 4;
  int nt = fi % NTt, ks = fi / NTt;
  int k = ks * 32 + ((l >> 4) << 3) + j;
  int n = (nt << 4) + (l & 15);
  float v;
  if (n < nsplit) v = s1[(size_t)k * nsplit + n];
  else            v = s2[(size_t)k * (N - nsplit) + (n - nsplit)];
  dst[idx] = (f16)v;
}

// =====================================================================
// xw = x @ Wih + (bih + bhh), f16 out. 2048 WG x 256 thr; wave = 16 rows.
// Swapped GEMM (Wih = A, x rows = B): C row = outdim (4 consecutive per
// lane) -> f16x4 stores.
// =====================================================================
__global__ __launch_bounds__(256) void xw_kernel(
    const float* __restrict__ x, const f16* __restrict__ pk,
    const float* __restrict__ bih, const float* __restrict__ bhh,
    f16* __restrict__ xw) {
  __shared__ float bs[512];
  const int tid = threadIdx.x, lane = tid & 63, w = tid >> 6;
  const int colv = lane & 15, l4 = lane >> 4;
  const int m0 = blockIdx.x * 64 + w * 16;
  const int t = m0 >> 8, b0 = m0 & 255;
  for (int i = tid; i < 512; i += 256) bs[i] = bih[i] + bhh[i];
  __syncthreads();
  f16x8 xB[4];
  const float* xr = x + ((size_t)(b0 + colv) * T_LEN + t) * DIMX;
#pragma unroll
  for (int ks = 0; ks < 4; ++ks) xB[ks] = cvt8(xr + ks * 32 + l4 * 8);
  f32x4 acc[32]; zacc<32>(acc);
#pragma unroll
  for (int ks = 0; ks < 4; ++ks)
#pragma unroll
    for (int mt = 0; mt < 32; ++mt)
      acc[mt] = MFMA16(*(const f16x8*)(pk + PK_WIH + ((size_t)(ks * 32 + mt) << 9) + (lane << 3)),
                       xB[ks], acc[mt]);
  f16* xo = xw + ((size_t)t * BATCH + b0 + colv) * RHD;
#pragma unroll
  for (int mt = 0; mt < 32; ++mt) {
    f16x4 v;
#pragma unroll
    for (int r = 0; r < 4; ++r) v[r] = (f16)(acc[mt][r] + bs[mt * 16 + l4 * 4 + r]);
    *(f16x4*)(xo + mt * 16 + l4 * 4) = v;
  }
}

// =====================================================================
// RNN scan: 16 WG x 512 thr (8 waves, 2/SIMD -> 256 VGPR/lane).
// Whh fully on-chip: K-slices 0..11 as register A-frags (192 VGPR/lane),
// slices 12..15 in LDS (128KB). Per step: h = relu(Whh@h + xw[t]);
// h overwrites xw[t] in place (same thread, same address).
// =====================================================================
__global__ __launch_bounds__(512, 2) void rnn_kernel(
    const f16* __restrict__ pk, const float* __restrict__ h0,
    f16* __restrict__ xw) {
  __shared__ __align__(16) f16 whh_lds[65536];  // slices 12..15
  __shared__ __align__(16) f16 h_st[16][520];
  const int tid = threadIdx.x, lane = tid & 63, w = tid >> 6;
  const int colv = lane & 15, l4 = lane >> 4;
  const int b0 = blockIdx.x * 16;

  {
    const uint4* src = (const uint4*)(pk + PK_WHH + 196608u);  // frag 384*512
    for (int i = tid; i < 8192; i += 512) ((uint4*)whh_lds)[i] = src[i];
  }
  f16x8 whhA[4][12];
#pragma unroll
  for (int mt = 0; mt < 4; ++mt)
#pragma unroll
    for (int ks = 0; ks < 12; ++ks)
      whhA[mt][ks] = *(const f16x8*)(pk + PK_WHH +
          ((size_t)(ks * 32 + 4 * w + mt) << 9) + (lane << 3));

  for (int i = tid; i < 16 * RHD; i += 512) h_st[i >> 9][i & 511] = (f16)h0[i & 511];
  __syncthreads();

#pragma unroll 1
  for (int t = 0; t < T_LEN; ++t) {
    f16* xwr = xw + ((size_t)t * BATCH + b0 + colv) * RHD;
    f16x4 xwv[4];
#pragma unroll
    for (int mt = 0; mt < 4; ++mt)
      xwv[mt] = *(const f16x4*)(xwr + (4 * w + mt) * 16 + l4 * 4);

    f32x4 acc[4]; zacc<4>(acc);
#pragma unroll
    for (int kc = 0; kc < 3; ++kc) {
      f16x8 B4[4];
#pragma unroll
      for (int kk = 0; kk < 4; ++kk)
        B4[kk] = *(const f16x8*)&h_st[colv][(kc * 4 + kk) * 32 + l4 * 8];
#pragma unroll
      for (int kk = 0; kk < 4; ++kk)
#pragma unroll
        for (int mt = 0; mt < 4; ++mt)
          acc[mt] = MFMA16(whhA[mt][kc * 4 + kk], B4[kk], acc[mt]);
    }
    {
      f16x8 B4[4];
#pragma unroll
      for (int kk = 0; kk < 4; ++kk)
        B4[kk] = *(const f16x8*)&h_st[colv][(12 + kk) * 32 + l4 * 8];
#pragma unroll
      for (int kk = 0; kk < 4; ++kk)
#pragma unroll
        for (int mt = 0; mt < 4; ++mt)
          acc[mt] = MFMA16(*(const f16x8*)(whh_lds +
              (((kk * 32 + 4 * w + mt) << 6) + lane) * 8), B4[kk], acc[mt]);
    }
    __syncthreads();  // B1: all h_st reads complete
#pragma unroll
    for (int mt = 0; mt < 4; ++mt) {
      f16x4 h4;
#pragma unroll
      for (int r = 0; r < 4; ++r)
        h4[r] = (f16)fmaxf(acc[mt][r] + (float)xwv[mt][r], 0.f);
      *(f16x4*)&h_st[colv][(4 * w + mt) * 16 + l4 * 4] = h4;
      *(f16x4*)(xwr + (4 * w + mt) * 16 + l4 * 4) = h4;  // h overwrites xw[t]
    }
    __syncthreads();  // B2
  }
}

// =====================================================================
// z scan: 16 WG x 512 thr. cbh in LDS (128KB A-frags), cbml as register
// A-frags (128 VGPR/lane). Full K per wave -> no partial exchange.
// hc = 0.5*(tanh(cbh@z + chb) + h); [mu|lv] = cbml@hc; z = mu+eps*exp(lv/2)
// =====================================================================
__global__ __launch_bounds__(512, 2) void zscan_kernel(
    const f16* __restrict__ pk, const f16* __restrict__ rnn_out,
    const float* __restrict__ chb, const float* __restrict__ cmb,
    const float* __restrict__ clb, const float* __restrict__ zq0,
    const float* __restrict__ eps_comb,
    f16* __restrict__ z_all, f16* __restrict__ mu_all, f16* __restrict__ lv_all) {
  __shared__ __align__(16) f16 cbh_lds[65536];  // 128KB
  __shared__ __align__(16) f16 hc_st[16][520];
  __shared__ __align__(16) f16 z_st[16][136];
  __shared__ __align__(16) f16 m_st[16][264];
  const int tid = threadIdx.x, lane = tid & 63, w = tid >> 6;
  const int colv = lane & 15, l4 = lane >> 4;
  const int b0 = blockIdx.x * 16;

  {
    const uint4* src = (const uint4*)(pk + PK_CBH);
    for (int i = tid; i < 8192; i += 512) ((uint4*)cbh_lds)[i] = src[i];
  }
  f16x8 cbmlA[2][16];
#pragma unroll
  for (int mt = 0; mt < 2; ++mt)
#pragma unroll
    for (int ks = 0; ks < 16; ++ks)
      cbmlA[mt][ks] = *(const f16x8*)(pk + PK_CBML +
          ((size_t)(ks * 16 + 2 * w + mt) << 9) + (lane << 3));

  float chbv[4][4];
#pragma unroll
  for (int mt = 0; mt < 4; ++mt)
#pragma unroll
    for (int r = 0; r < 4; ++r)
      chbv[mt][r] = chb[(4 * w + mt) * 16 + l4 * 4 + r];
  // z-epilogue mapping: thread -> (batch be, dims d0..d0+3)
  const int be = tid >> 5, d0 = (tid & 31) * 4;
  const float4 cmbv = *(const float4*)(cmb + d0);
  const float4 clbv = *(const float4*)(clb + d0);

  for (int i = tid; i < 16 * ZDIM; i += 512) {
    f16 zv = (f16)zq0[i & 127];
    z_st[i >> 7][i & 127] = zv;
    z_all[(size_t)(b0 + (i >> 7)) * ZDIM + (i & 127)] = zv;  // z_all[0]
  }
  __syncthreads();

#pragma unroll 1
  for (int t = 0; t < T_LEN; ++t) {
    // prefetch h_rnn + eps (global, consumed later)
    const f16* hr = rnn_out + ((size_t)t * BATCH + b0 + colv) * RHD;
    f16x4 hv[4];
#pragma unroll
    for (int mt = 0; mt < 4; ++mt)
      hv[mt] = *(const f16x4*)(hr + (4 * w + mt) * 16 + l4 * 4);
    float4 ep = *(const float4*)(eps_comb + ((size_t)t * BATCH + b0 + be) * ZDIM + d0);

    // GEMM1: cbh @ z (M=512, K=128)
    f16x8 zB[4];
#pragma unroll
    for (int ks = 0; ks < 4; ++ks)
      zB[ks] = *(const f16x8*)&z_st[colv][ks * 32 + l4 * 8];
    f32x4 a1[4]; zacc<4>(a1);
#pragma unroll
    for (int ks = 0; ks < 4; ++ks)
#pragma unroll
      for (int mt = 0; mt < 4; ++mt)
        a1[mt] = MFMA16(*(const f16x8*)(cbh_lds +
            (((ks * 32 + 4 * w + mt) << 6) + lane) * 8), zB[ks], a1[mt]);
    // epilogue1: hc
#pragma unroll
    for (int mt = 0; mt < 4; ++mt) {
      f16x4 hc4;
#pragma unroll
      for (int r = 0; r < 4; ++r) {
        float cs = a1[mt][r] + chbv[mt][r];
        float tt = __builtin_amdgcn_exp2f(cs * 2.885390082f);   // e^(2x)
        float th = 1.f - 2.f * __builtin_amdgcn_rcpf(tt + 1.f); // tanh
        hc4[r] = (f16)(0.5f * (th + (float)hv[mt][r]));
      }
      *(f16x4*)&hc_st[colv][(4 * w + mt) * 16 + l4 * 4] = hc4;
    }
    __syncthreads();  // B1: hc_st ready (and prior z_st reads done)

    // GEMM2: cbml @ hc (M=256, K=512)
    f32x4 a2[2]; zacc<2>(a2);
#pragma unroll
    for (int kc = 0; kc < 4; ++kc) {
      f16x8 hcB[4];
#pragma unroll
      for (int kk = 0; kk < 4; ++kk)
        hcB[kk] = *(const f16x8*)&hc_st[colv][(kc * 4 + kk) * 32 + l4 * 8];
#pragma unroll
      for (int kk = 0; kk < 4; ++kk)
#pragma unroll
        for (int mt = 0; mt < 2; ++mt)
          a2[mt] = MFMA16(cbmlA[mt][kc * 4 + kk], hcB[kk], a2[mt]);
    }
#pragma unroll
    for (int mt = 0; mt < 2; ++mt) {
      f16x4 v;
#pragma unroll
      for (int r = 0; r < 4; ++r) v[r] = (f16)a2[mt][r];
      *(f16x4*)&m_st[colv][(2 * w + mt) * 16 + l4 * 4] = v;
    }
    __syncthreads();  // B2: m_st ready

    // z epilogue: thread -> (be, d0..d0+3)
    {
      f16x4 muf = *(const f16x4*)&m_st[be][d0];
      f16x4 lvf = *(const f16x4*)&m_st[be][128 + d0];
      float epv[4] = {ep.x, ep.y, ep.z, ep.w};
      float cmv[4] = {cmbv.x, cmbv.y, cmbv.z, cmbv.w};
      float clv[4] = {clbv.x, clbv.y, clbv.z, clbv.w};
      f16x4 z4, mu4, lv4;
#pragma unroll
      for (int r = 0; r < 4; ++r) {
        float mu = (float)muf[r] + cmv[r];
        float lv = (float)lvf[r] + clv[r];
        float zv = mu + epv[r] * __builtin_amdgcn_exp2f(lv * 0.7213475204f);
        z4[r] = (f16)zv; mu4[r] = (f16)mu; lv4[r] = (f16)lv;
      }
      *(f16x4*)&z_st[be][d0] = z4;
      size_t o = ((size_t)t * BATCH + b0 + be) * ZDIM + d0;
      *(f16x4*)(z_all + o + (size_t)BATCH * ZDIM) = z4;  // slot t+1
      *(f16x4*)(mu_all + o) = mu4;
      *(f16x4*)(lv_all + o) = lv4;
    }
    __syncthreads();  // B3: z_st/m_st safe for next step
  }
}

// =====================================================================
// Phase D: parallel transition/emitter/losses over all (t,b). (unchanged)
// =====================================================================
__global__ __launch_bounds__(256) void dpar_kernel(
    const f16* __restrict__ z_all, const f16* __restrict__ mu_all,
    const f16* __restrict__ lv_all, const float* __restrict__ y,
    const float* __restrict__ eps_emit, const f16* __restrict__ pk,
    const float* __restrict__ g1b, const float* __restrict__ g2b,
    const float* __restrict__ p1b, const float* __restrict__ p2b,
    const float* __restrict__ tmub, const float* __restrict__ tlvb,
    const float* __restrict__ e1b, const float* __restrict__ e2b,
    const float* __restrict__ emub, const float* __restrict__ em_logvar,
    float* __restrict__ partials) {
  __shared__ __align__(16) f16 sb256[4][16 * 264];
  __shared__ __align__(16) f16 sb128[4][16 * 136];
  __shared__ float wsum[4][2];
  const int tid = threadIdx.x, lane = tid & 63, w = tid >> 6;
  const int colv = lane & 15, rb = (lane >> 4) << 2;
  const int m0 = blockIdx.x * 64 + w * 16;
  const int t = m0 >> 8, b0 = m0 & 255;
  f16* B256 = &sb256[w][0];
  f16* B128 = &sb128[w][0];

  f16x8 zp[4], zt[4];
  const f16* zpr = z_all + ((size_t)t * BATCH + b0) * ZDIM;
#pragma unroll
  for (int ks = 0; ks < 4; ++ks) {
    zp[ks] = *(const f16x8*)(zpr + (size_t)colv * ZDIM + ks * 32 + ((lane >> 4) << 3));
    zt[ks] = *(const f16x8*)(zpr + (size_t)BATCH * ZDIM + (size_t)colv * ZDIM + ks * 32 + ((lane >> 4) << 3));
  }

  f32x4 a16[16], a8[8];
  f16x8 af[8], af4[4];
  zacc<16>(a16); gemm_regA<4, 16>(zp, pk + PK_G1, lane, a16);
  store_relu<16>(a16, g1b, B256, 264, lane); ldsfence();
  load_af<8>(B256, 264, lane, af); ldsfence();
  zacc<8>(a8); gemm_regA<8, 8>(af, pk + PK_G2, lane, a8);
  f32x4 gate[8];
#pragma unroll
  for (int j = 0; j < 8; ++j)
#pragma unroll
    for (int r = 0; r < 4; ++r)
      gate[j][r] = 1.f / (1.f + expf(-(a8[j][r] + g2b[j * 16 + colv])));
  zacc<16>(a16); gemm_regA<4, 16>(zp, pk + PK_P1, lane, a16);
  store_relu<16>(a16, p1b, B256, 264, lane); ldsfence();
  load_af<8>(B256, 264, lane, af); ldsfence();
  zacc<8>(a8); gemm_regA<8, 8>(af, pk + PK_P2, lane, a8);
  f32x4 prop[8];
#pragma unroll
  for (int j = 0; j < 8; ++j)
#pragma unroll
    for (int r = 0; r < 4; ++r) {
      float v = a8[j][r] + p2b[j * 16 + colv];
      prop[j][r] = v;
      B128[(rb + r) * 136 + j * 16 + colv] = (f16)fmaxf(v, 0.f);
    }
  ldsfence();
  zacc<8>(a8); gemm_regA<4, 8>(zp, pk + PK_TMU, lane, a8);
  f32x4 prmu[8];
#pragma unroll
  for (int j = 0; j < 8; ++j)
#pragma unroll
    for (int r = 0; r < 4; ++r) {
      float gg = gate[j][r];
      prmu[j][r] = (1.f - gg) * (a8[j][r] + tmub[j * 16 + colv]) + gg * prop[j][r];
    }
  load_af<4>(B128, 136, lane, af4); ldsfence();
  zacc<8>(a8); gemm_regA<4, 8>(af4, pk + PK_TLV, lane, a8);
  f32x4 prlv[8];
#pragma unroll
  for (int j = 0; j < 8; ++j)
#pragma unroll
    for (int r = 0; r < 4; ++r) prlv[j][r] = a8[j][r] + tlvb[j * 16 + colv];
  zacc<16>(a16); gemm_regA<4, 16>(zt, pk + PK_E1, lane, a16);
  store_relu<16>(a16, e1b, B256, 264, lane); ldsfence();
  load_af<8>(B256, 264, lane, af); ldsfence();
  zacc<16>(a16); gemm_regA<8, 16>(af, pk + PK_E2, lane, a16);
  store_relu<16>(a16, e2b, B256, 264, lane); ldsfence();
  load_af<8>(B256, 264, lane, af); ldsfence();
  zacc<8>(a8); gemm_regA<8, 8>(af, pk + PK_EMU, lane, a8);
  float srec = 0.f, skl = 0.f;
#pragma unroll
  for (int j = 0; j < 8; ++j)
#pragma unroll
    for (int r = 0; r < 4; ++r) {
      int row = rb + r, n = j * 16 + colv;
      size_t tb = (size_t)t * BATCH + b0 + row;
      float xt = a8[j][r] + emub[n] + eps_emit[tb * DIMX + n] * expf(0.5f * em_logvar[n]);
      float dy = xt - y[((size_t)(b0 + row) * T_LEN + t) * DIMX + n];
      srec += dy * dy;
      float m_ = (float)mu_all[tb * ZDIM + n], l_ = (float)lv_all[tb * ZDIM + n];
      float dm = m_ - prmu[j][r];
      skl += 0.5f * (prlv[j][r] - l_ + (expf(l_) + dm * dm) * expf(-prlv[j][r]) - 1.f);
    }
#pragma unroll
  for (int off = 32; off; off >>= 1) {
    srec += __shfl_xor(srec, off);
    skl += __shfl_xor(skl, off);
  }
  if (lane == 0) { wsum[w][0] = srec; wsum[w][1] = skl; }
  __syncthreads();
  if (tid == 0) {
    partials[blockIdx.x * 2 + 0] = wsum[0][0] + wsum[1][0] + wsum[2][0] + wsum[3][0];
    partials[blockIdx.x * 2 + 1] = wsum[0][1] + wsum[1][1] + wsum[2][1] + wsum[3][1];
  }
}

// =====================================================================
__global__ void finalize_kernel(const float* __restrict__ partials, float* __restrict__ out) {
  __shared__ float sm[256][2];
  int tid = threadIdx.x;
  float r = 0.f, kk = 0.f;
  for (int i = tid; i < 2048; i += 256) {
    r += partials[2 * i];
    kk += partials[2 * i + 1];
  }
  sm[tid][0] = r; sm[tid][1] = kk;
  __syncthreads();
  for (int off = 128; off; off >>= 1) {
    if (tid < off) { sm[tid][0] += sm[tid + off][0]; sm[tid][1] += sm[tid + off][1]; }
    __syncthreads();
  }
  if (tid == 0) {
    out[0] = sm[0][0] / (131072.f * 128.f);
    out[1] = sm[0][1] / 131072.f;
  }
}

// =====================================================================
extern "C" void kernel_launch(void* const* d_in, const int* in_sizes, int n_in,
                              void* d_out, int out_size, void* d_ws, size_t ws_size,
                              hipStream_t stream) {
  (void)in_sizes; (void)n_in; (void)out_size;
  const float* x        = (const float*)d_in[0];
  const float* y        = (const float*)d_in[1];
  const float* eps_comb = (const float*)d_in[2];
  const float* eps_emit = (const float*)d_in[3];
  const float* wih = (const float*)d_in[4];
  const float* whh = (const float*)d_in[5];
  const float* bih = (const float*)d_in[6];
  const float* bhh = (const float*)d_in[7];
  const float* h0  = (const float*)d_in[8];
  const float* zq0 = (const float*)d_in[9];
  const float* g1W = (const float*)d_in[10]; const float* g1b = (const float*)d_in[11];
  const float* g2W = (const float*)d_in[12]; const float* g2b = (const float*)d_in[13];
  const float* p1W = (const float*)d_in[14]; const float* p1b = (const float*)d_in[15];
  const float* p2W = (const float*)d_in[16]; const float* p2b = (const float*)d_in[17];
  const float* tmuW = (const float*)d_in[18]; const float* tmub = (const float*)d_in[19];
  const float* tlvW = (const float*)d_in[20]; const float* tlvb = (const float*)d_in[21];
  const float* chW = (const float*)d_in[22]; const float* chb = (const float*)d_in[23];
  const float* cmW = (const float*)d_in[24]; const float* cmb = (const float*)d_in[25];
  const float* clW = (const float*)d_in[26]; const float* clb = (const float*)d_in[27];
  const float* e1W = (const float*)d_in[28]; const float* e1b = (const float*)d_in[29];
  const float* e2W = (const float*)d_in[30]; const float* e2b = (const float*)d_in[31];
  const float* emW = (const float*)d_in[32]; const float* emb = (const float*)d_in[33];
  const float* elv = (const float*)d_in[34];

  char* ws = (char*)d_ws;
  f16*  xw      = (f16*)(ws + WS_XW);
  f16*  z_all   = (f16*)(ws + WS_Z);
  f16*  mu_all  = (f16*)(ws + WS_MU);
  f16*  lv_all  = (f16*)(ws + WS_LV);
  f16*  pk      = (f16*)(ws + WS_PK);
  float* partials = (float*)(ws + WS_PART);
  float* out = (float*)d_out;
  if (ws_size < WS_END) return;

#define PACK(S1, S2, NS_, K, N, OFF) \
  pack_kernel<<<dim3(((K) * (N)) / 256), dim3(256), 0, stream>>>(S1, S2, NS_, K, N, pk + (OFF))
  PACK(wih, wih, 512, 128, 512, PK_WIH);
  PACK(whh, whh, 512, 512, 512, PK_WHH);
  PACK(g1W, g1W, 256, 128, 256, PK_G1);
  PACK(g2W, g2W, 128, 256, 128, PK_G2);
  PACK(p1W, p1W, 256, 128, 256, PK_P1);
  PACK(p2W, p2W, 128, 256, 128, PK_P2);
  PACK(tmuW, tmuW, 128, 128, 128, PK_TMU);
  PACK(tlvW, tlvW, 128, 128, 128, PK_TLV);
  PACK(chW, chW, 512, 128, 512, PK_CBH);
  PACK(cmW, clW, 128, 512, 256, PK_CBML);
  PACK(e1W, e1W, 256, 128, 256, PK_E1);
  PACK(e2W, e2W, 256, 256, 256, PK_E2);
  PACK(emW, emW, 128, 256, 128, PK_EMU);
#undef PACK

  xw_kernel<<<dim3(2048), dim3(256), 0, stream>>>(x, pk, bih, bhh, xw);
  rnn_kernel<<<dim3(16), dim3(512), 0, stream>>>(pk, h0, xw);
  zscan_kernel<<<dim3(16), dim3(512), 0, stream>>>(pk, xw, chb, cmb, clb, zq0,
                                                   eps_comb, z_all, mu_all, lv_all);
  dpar_kernel<<<dim3(2048), dim3(256), 0, stream>>>(z_all, mu_all, lv_all, y, eps_emit, pk,
                                                    g1b, g2b, p1b, p2b, tmub, tlvb, e1b, e2b,
                                                    emb, elv, partials);
  finalize_kernel<<<dim3(1), dim3(256), 0, stream>>>(partials, out);
}

// Round 5
// 3108.683 us; speedup vs baseline: 4.7718x; 1.0748x over previous
//
#include <hip/hip_runtime.h>

// Deep Kalman Filter inference, MI355X/gfx950.
// Phases: pack (weights -> fp16 MFMA fragments), xw = x@Wih+bias (parallel),
// rnn scan (16 WG, Whh on-chip: 192 VGPR pinned + 128KB LDS, xw prefetch),
// z scan (16 WG, cbh LDS + cbml regs pinned, h/eps prefetch),
// transition/emitter/loss (2048 WG), finalize.
// R3 lesson: weight residency must fit the 512KB/CU reg file + 160KB LDS.
// R4 lesson: compiler remats "register-resident" weights unless pinned via
// asm; same-step global loads expose ~1us HBM latency -> prefetch t+1.

#define T_LEN 512
#define BATCH 256
#define DIMX  128
#define ZDIM  128
#define RHD   512

typedef _Float16 f16;
typedef _Float16 f16x4 __attribute__((ext_vector_type(4)));
typedef _Float16 f16x8 __attribute__((ext_vector_type(8)));
typedef float    f32x4 __attribute__((ext_vector_type(4)));

#define MFMA16(a,b,c) __builtin_amdgcn_mfma_f32_16x16x32_f16((a),(b),(c),0,0,0)

// ---- packed weight element offsets (f16 elements) ----
#define PK_WIH  0u
#define PK_WHH  65536u
#define PK_G1   327680u
#define PK_G2   360448u
#define PK_P1   393216u
#define PK_P2   425984u
#define PK_TMU  458752u
#define PK_TLV  475136u
#define PK_CBH  491520u
#define PK_CBML 557056u
#define PK_E1   688128u
#define PK_E2   720896u
#define PK_EMU  786432u

// ---- workspace byte offsets ----
#define WS_XW   0ull                          // f16 [T][B][RH]: xw in, h out (aliased)
#define WS_Z    (WS_XW  + 134217728ull)       // f16 [T+1][B][Z]
#define WS_MU   (WS_Z   + 33619968ull)        // f16 [T][B][Z]
#define WS_LV   (WS_MU  + 33554432ull)        // f16 [T][B][Z]
#define WS_PK   (WS_LV  + 33554432ull)        // f16 packed weights
#define WS_PART (WS_PK  + 1638400ull)         // f32 [2048][2]
#define WS_END  (WS_PART + 16384ull)

// =====================================================================
// helpers
// =====================================================================
__device__ __forceinline__ void ldsfence() {
  asm volatile("s_waitcnt lgkmcnt(0)" ::: "memory");
  __builtin_amdgcn_sched_barrier(0);
}

// Anti-rematerialization pin: value becomes an (unrecomputable) asm output.
__device__ __forceinline__ void pin8(f16x8& v) {
  f32x4 t = __builtin_bit_cast(f32x4, v);
  asm volatile("" : "+v"(t));
  v = __builtin_bit_cast(f16x8, t);
}

template<int N>
__device__ __forceinline__ void zacc(f32x4* a) {
  f32x4 z = {0.f, 0.f, 0.f, 0.f};
#pragma unroll
  for (int i = 0; i < N; ++i) a[i] = z;
}

__device__ __forceinline__ f16x8 cvt8(const float* p) {
  float4 a = *(const float4*)p, b = *(const float4*)(p + 4);
  f16x8 r;
  r[0] = (f16)a.x; r[1] = (f16)a.y; r[2] = (f16)a.z; r[3] = (f16)a.w;
  r[4] = (f16)b.x; r[5] = (f16)b.y; r[6] = (f16)b.z; r[7] = (f16)b.w;
  return r;
}

// A-frag load from LDS tile [16][stride] (row = lane&15). (dpar)
template<int KS>
__device__ __forceinline__ void load_af(const f16* src, int sstr, int lane, f16x8* af) {
#pragma unroll
  for (int ks = 0; ks < KS; ++ks)
    af[ks] = *(const f16x8*)(src + (lane & 15) * sstr + ks * 32 + ((lane >> 4) << 3));
}

template<int KS, int NT>
__device__ __forceinline__ void gemm_regA(const f16x8* af, const f16* __restrict__ bp,
                                          int lane, f32x4* acc) {
#pragma unroll
  for (int ks = 0; ks < KS; ++ks)
#pragma unroll
    for (int j = 0; j < NT; ++j) {
      f16x8 bf = *(const f16x8*)(bp + (((size_t)(ks * NT + j)) << 9) + (lane << 3));
      acc[j] = MFMA16(af[ks], bf, acc[j]);
    }
}

template<int NT>
__device__ __forceinline__ void store_relu(const f32x4* acc, const float* __restrict__ bias,
                                           f16* dst, int dstr, int lane) {
  int colv = lane & 15, rb = (lane >> 4) << 2;
#pragma unroll
  for (int j = 0; j < NT; ++j)
#pragma unroll
    for (int r = 0; r < 4; ++r)
      dst[(rb + r) * dstr + j * 16 + colv] = (f16)fmaxf(acc[j][r] + bias[j * 16 + colv], 0.f);
}

// =====================================================================
// pack: W[K][N] fp32 -> fp16 fragments (frag fi = ks*(N/16) + nt).
// element (k,n): k = ks*32 + (l>>4)*8 + j, n = nt*16 + (l&15)
// =====================================================================
__global__ void pack_kernel(const float* __restrict__ s1, const float* __restrict__ s2,
                            int nsplit, int K, int N, f16* __restrict__ dst) {
  int idx = blockIdx.x * 256 + threadIdx.x;
  if (idx >= K * N) return;
  int j = idx & 7, l = (idx >> 3) & 63, fi = idx >> 9;
  int NTt = N >> 4;
  int nt = fi % NTt, ks = fi / NTt;
  int k = ks * 32 + ((l >> 4) << 3) + j;
  int n = (nt << 4) + (l & 15);
  float v;
  if (n < nsplit) v = s1[(size_t)k * nsplit + n];
  else            v = s2[(size_t)k * (N - nsplit) + (n - nsplit)];
  dst[idx] = (f16)v;
}

// =====================================================================
// xw = x @ Wih + (bih + bhh), f16 out. 2048 WG x 256 thr; wave = 16 rows.
// =====================================================================
__global__ __launch_bounds__(256) void xw_kernel(
    const float* __restrict__ x, const f16* __restrict__ pk,
    const float* __restrict__ bih, const float* __restrict__ bhh,
    f16* __restrict__ xw) {
  __shared__ float bs[512];
  const int tid = threadIdx.x, lane = tid & 63, w = tid >> 6;
  const int colv = lane & 15, l4 = lane >> 4;
  const int m0 = blockIdx.x * 64 + w * 16;
  const int t = m0 >> 8, b0 = m0 & 255;
  for (int i = tid; i < 512; i += 256) bs[i] = bih[i] + bhh[i];
  __syncthreads();
  f16x8 xB[4];
  const float* xr = x + ((size_t)(b0 + colv) * T_LEN + t) * DIMX;
#pragma unroll
  for (int ks = 0; ks < 4; ++ks) xB[ks] = cvt8(xr + ks * 32 + l4 * 8);
  f32x4 acc[32]; zacc<32>(acc);
#pragma unroll
  for (int ks = 0; ks < 4; ++ks)
#pragma unroll
    for (int mt = 0; mt < 32; ++mt)
      acc[mt] = MFMA16(*(const f16x8*)(pk + PK_WIH + ((size_t)(ks * 32 + mt) << 9) + (lane << 3)),
                       xB[ks], acc[mt]);
  f16* xo = xw + ((size_t)t * BATCH + b0 + colv) * RHD;
#pragma unroll
  for (int mt = 0; mt < 32; ++mt) {
    f16x4 v;
#pragma unroll
    for (int r = 0; r < 4; ++r) v[r] = (f16)(acc[mt][r] + bs[mt * 16 + l4 * 4 + r]);
    *(f16x4*)(xo + mt * 16 + l4 * 4) = v;
  }
}

// =====================================================================
// RNN scan: 16 WG x 512 thr (8 waves, 2/SIMD -> 256 VGPR/lane).
// Whh on-chip: K-slices 0..11 as PINNED register A-frags (192 VGPR),
// slices 12..15 in LDS (128KB). xw[t+1] prefetched during step t.
// h overwrites xw[t] in place.
// =====================================================================
__global__ __launch_bounds__(512, 2) void rnn_kernel(
    const f16* __restrict__ pk, const float* __restrict__ h0,
    f16* __restrict__ xw) {
  __shared__ __align__(16) f16 whh_lds[65536];  // slices 12..15
  __shared__ __align__(16) f16 h_st[16][520];
  const int tid = threadIdx.x, lane = tid & 63, w = tid >> 6;
  const int colv = lane & 15, l4 = lane >> 4;
  const int b0 = blockIdx.x * 16;

  {
    const uint4* src = (const uint4*)(pk + PK_WHH + 196608u);  // frags 384..511
    for (int i = tid; i < 8192; i += 512) ((uint4*)whh_lds)[i] = src[i];
  }
  f16x8 whhA[4][12];
#pragma unroll
  for (int mt = 0; mt < 4; ++mt)
#pragma unroll
    for (int ks = 0; ks < 12; ++ks) {
      whhA[mt][ks] = *(const f16x8*)(pk + PK_WHH +
          ((size_t)(ks * 32 + 4 * w + mt) << 9) + (lane << 3));
      pin8(whhA[mt][ks]);
    }

  for (int i = tid; i < 16 * RHD; i += 512) h_st[i >> 9][i & 511] = (f16)h0[i & 511];
  __syncthreads();

  const int off0 = (4 * w) * 16 + l4 * 4;
  f16* xp = xw + (size_t)(b0 + colv) * RHD;  // [t=0] row for this lane
  f16x4 xwc[4], xwn[4];
#pragma unroll
  for (int mt = 0; mt < 4; ++mt) xwc[mt] = *(const f16x4*)(xp + off0 + mt * 16);

#pragma unroll 1
  for (int t = 0; t < T_LEN; ++t) {
    // prefetch xw[t+1] (issued now, consumed next iteration)
    f16* xpn = (t < T_LEN - 1) ? (xp + (size_t)BATCH * RHD) : xp;
#pragma unroll
    for (int mt = 0; mt < 4; ++mt) xwn[mt] = *(const f16x4*)(xpn + off0 + mt * 16);

    f32x4 acc[4]; zacc<4>(acc);
#pragma unroll
    for (int kc = 0; kc < 6; ++kc) {
      f16x8 B2[2];
#pragma unroll
      for (int kk = 0; kk < 2; ++kk)
        B2[kk] = *(const f16x8*)&h_st[colv][(kc * 2 + kk) * 32 + l4 * 8];
#pragma unroll
      for (int kk = 0; kk < 2; ++kk)
#pragma unroll
        for (int mt = 0; mt < 4; ++mt)
          acc[mt] = MFMA16(whhA[mt][kc * 2 + kk], B2[kk], acc[mt]);
    }
#pragma unroll
    for (int kc = 0; kc < 2; ++kc) {
      f16x8 B2[2];
#pragma unroll
      for (int kk = 0; kk < 2; ++kk)
        B2[kk] = *(const f16x8*)&h_st[colv][(12 + kc * 2 + kk) * 32 + l4 * 8];
#pragma unroll
      for (int kk = 0; kk < 2; ++kk)
#pragma unroll
        for (int mt = 0; mt < 4; ++mt)
          acc[mt] = MFMA16(*(const f16x8*)(whh_lds +
              ((((kc * 2 + kk) * 32 + 4 * w + mt) << 6) + lane) * 8), B2[kk], acc[mt]);
    }
    __syncthreads();  // B1: all h_st reads complete
#pragma unroll
    for (int mt = 0; mt < 4; ++mt) {
      f16x4 h4;
#pragma unroll
      for (int r = 0; r < 4; ++r)
        h4[r] = (f16)fmaxf(acc[mt][r] + (float)xwc[mt][r], 0.f);
      *(f16x4*)&h_st[colv][(4 * w + mt) * 16 + l4 * 4] = h4;
      *(f16x4*)(xp + off0 + mt * 16) = h4;  // h overwrites xw[t]
    }
    __syncthreads();  // B2
    xp = xpn;
#pragma unroll
    for (int mt = 0; mt < 4; ++mt) xwc[mt] = xwn[mt];
  }
}

// =====================================================================
// z scan: 16 WG x 512 thr. cbh in LDS (128KB), cbml as PINNED register
// A-frags (128 VGPR). h_rnn/eps for t+1 prefetched during step t.
// =====================================================================
__global__ __launch_bounds__(512, 2) void zscan_kernel(
    const f16* __restrict__ pk, const f16* __restrict__ rnn_out,
    const float* __restrict__ chb, const float* __restrict__ cmb,
    const float* __restrict__ clb, const float* __restrict__ zq0,
    const float* __restrict__ eps_comb,
    f16* __restrict__ z_all, f16* __restrict__ mu_all, f16* __restrict__ lv_all) {
  __shared__ __align__(16) f16 cbh_lds[65536];  // 128KB
  __shared__ __align__(16) f16 hc_st[16][520];
  __shared__ __align__(16) f16 z_st[16][136];
  __shared__ __align__(16) f16 m_st[16][264];
  const int tid = threadIdx.x, lane = tid & 63, w = tid >> 6;
  const int colv = lane & 15, l4 = lane >> 4;
  const int b0 = blockIdx.x * 16;

  {
    const uint4* src = (const uint4*)(pk + PK_CBH);
    for (int i = tid; i < 8192; i += 512) ((uint4*)cbh_lds)[i] = src[i];
  }
  f16x8 cbmlA[2][16];
#pragma unroll
  for (int mt = 0; mt < 2; ++mt)
#pragma unroll
    for (int ks = 0; ks < 16; ++ks) {
      cbmlA[mt][ks] = *(const f16x8*)(pk + PK_CBML +
          ((size_t)(ks * 16 + 2 * w + mt) << 9) + (lane << 3));
      pin8(cbmlA[mt][ks]);
    }

  float chbv[4][4];
#pragma unroll
  for (int mt = 0; mt < 4; ++mt)
#pragma unroll
    for (int r = 0; r < 4; ++r)
      chbv[mt][r] = chb[(4 * w + mt) * 16 + l4 * 4 + r];
  // z-epilogue mapping: thread -> (batch be, dims d0..d0+3)
  const int be = tid >> 5, d0 = (tid & 31) * 4;
  const float4 cmbv = *(const float4*)(cmb + d0);
  const float4 clbv = *(const float4*)(clb + d0);

  for (int i = tid; i < 16 * ZDIM; i += 512) {
    f16 zv = (f16)zq0[i & 127];
    z_st[i >> 7][i & 127] = zv;
    z_all[(size_t)(b0 + (i >> 7)) * ZDIM + (i & 127)] = zv;  // z_all[0]
  }
  __syncthreads();

  const int hoff = (4 * w) * 16 + l4 * 4;
  const f16* hp = rnn_out + (size_t)(b0 + colv) * RHD;
  const float* epp = eps_comb + (size_t)(b0 + be) * ZDIM + d0;
  f16x4 hvc[4], hvn[4];
  float4 epc, epn;
#pragma unroll
  for (int mt = 0; mt < 4; ++mt) hvc[mt] = *(const f16x4*)(hp + hoff + mt * 16);
  epc = *(const float4*)epp;

#pragma unroll 1
  for (int t = 0; t < T_LEN; ++t) {
    // prefetch h_rnn/eps for t+1
    const f16* hpn = (t < T_LEN - 1) ? (hp + (size_t)BATCH * RHD) : hp;
    const float* eppn = (t < T_LEN - 1) ? (epp + (size_t)BATCH * ZDIM) : epp;
#pragma unroll
    for (int mt = 0; mt < 4; ++mt) hvn[mt] = *(const f16x4*)(hpn + hoff + mt * 16);
    epn = *(const float4*)eppn;

    // GEMM1: cbh @ z (M=512, K=128)
    f16x8 zB[4];
#pragma unroll
    for (int ks = 0; ks < 4; ++ks)
      zB[ks] = *(const f16x8*)&z_st[colv][ks * 32 + l4 * 8];
    f32x4 a1[4]; zacc<4>(a1);
#pragma unroll
    for (int ks = 0; ks < 4; ++ks)
#pragma unroll
      for (int mt = 0; mt < 4; ++mt)
        a1[mt] = MFMA16(*(const f16x8*)(cbh_lds +
            (((ks * 32 + 4 * w + mt) << 6) + lane) * 8), zB[ks], a1[mt]);
    // epilogue1: hc
#pragma unroll
    for (int mt = 0; mt < 4; ++mt) {
      f16x4 hc4;
#pragma unroll
      for (int r = 0; r < 4; ++r) {
        float cs = a1[mt][r] + chbv[mt][r];
        float tt = __builtin_amdgcn_exp2f(cs * 2.885390082f);   // e^(2x)
        float th = 1.f - 2.f * __builtin_amdgcn_rcpf(tt + 1.f); // tanh
        hc4[r] = (f16)(0.5f * (th + (float)hvc[mt][r]));
      }
      *(f16x4*)&hc_st[colv][(4 * w + mt) * 16 + l4 * 4] = hc4;
    }
    __syncthreads();  // B1: hc_st ready (and prior z_st reads done)

    // GEMM2: cbml @ hc (M=256, K=512)
    f32x4 a2[2]; zacc<2>(a2);
#pragma unroll
    for (int kc = 0; kc < 8; ++kc) {
      f16x8 hcB[2];
#pragma unroll
      for (int kk = 0; kk < 2; ++kk)
        hcB[kk] = *(const f16x8*)&hc_st[colv][(kc * 2 + kk) * 32 + l4 * 8];
#pragma unroll
      for (int kk = 0; kk < 2; ++kk)
#pragma unroll
        for (int mt = 0; mt < 2; ++mt)
          a2[mt] = MFMA16(cbmlA[mt][kc * 2 + kk], hcB[kk], a2[mt]);
    }
#pragma unroll
    for (int mt = 0; mt < 2; ++mt) {
      f16x4 v;
#pragma unroll
      for (int r = 0; r < 4; ++r) v[r] = (f16)a2[mt][r];
      *(f16x4*)&m_st[colv][(2 * w + mt) * 16 + l4 * 4] = v;
    }
    __syncthreads();  // B2: m_st ready

    // z epilogue: thread -> (be, d0..d0+3)
    {
      f16x4 muf = *(const f16x4*)&m_st[be][d0];
      f16x4 lvf = *(const f16x4*)&m_st[be][128 + d0];
      float epv[4] = {epc.x, epc.y, epc.z, epc.w};
      float cmv[4] = {cmbv.x, cmbv.y, cmbv.z, cmbv.w};
      float clv[4] = {clbv.x, clbv.y, clbv.z, clbv.w};
      f16x4 z4, mu4, lv4;
#pragma unroll
      for (int r = 0; r < 4; ++r) {
        float mu = (float)muf[r] + cmv[r];
        float lv = (float)lvf[r] + clv[r];
        float zv = mu + epv[r] * __builtin_amdgcn_exp2f(lv * 0.7213475204f);
        z4[r] = (f16)zv; mu4[r] = (f16)mu; lv4[r] = (f16)lv;
      }
      *(f16x4*)&z_st[be][d0] = z4;
      size_t o = ((size_t)t * BATCH + b0 + be) * ZDIM + d0;
      *(f16x4*)(z_all + o + (size_t)BATCH * ZDIM) = z4;  // slot t+1
      *(f16x4*)(mu_all + o) = mu4;
      *(f16x4*)(lv_all + o) = lv4;
    }
    __syncthreads();  // B3: z_st/m_st safe for next step
    hp = hpn; epp = eppn;
#pragma unroll
    for (int mt = 0; mt < 4; ++mt) hvc[mt] = hvn[mt];
    epc = epn;
  }
}

// =====================================================================
// Phase D: parallel transition/emitter/losses over all (t,b). (unchanged)
// =====================================================================
__global__ __launch_bounds__(256) void dpar_kernel(
    const f16* __restrict__ z_all, const f16* __restrict__ mu_all,
    const f16* __restrict__ lv_all, const float* __restrict__ y,
    const float* __restrict__ eps_emit, const f16* __restrict__ pk,
    const float* __restrict__ g1b, const float* __restrict__ g2b,
    const float* __restrict__ p1b, const float* __restrict__ p2b,
    const float* __restrict__ tmub, const float* __restrict__ tlvb,
    const float* __restrict__ e1b, const float* __restrict__ e2b,
    const float* __restrict__ emub, const float* __restrict__ em_logvar,
    float* __restrict__ partials) {
  __shared__ __align__(16) f16 sb256[4][16 * 264];
  __shared__ __align__(16) f16 sb128[4][16 * 136];
  __shared__ float wsum[4][2];
  const int tid = threadIdx.x, lane = tid & 63, w = tid >> 6;
  const int colv = lane & 15, rb = (lane >> 4) << 2;
  const int m0 = blockIdx.x * 64 + w * 16;
  const int t = m0 >> 8, b0 = m0 & 255;
  f16* B256 = &sb256[w][0];
  f16* B128 = &sb128[w][0];

  f16x8 zp[4], zt[4];
  const f16* zpr = z_all + ((size_t)t * BATCH + b0) * ZDIM;
#pragma unroll
  for (int ks = 0; ks < 4; ++ks) {
    zp[ks] = *(const f16x8*)(zpr + (size_t)colv * ZDIM + ks * 32 + ((lane >> 4) << 3));
    zt[ks] = *(const f16x8*)(zpr + (size_t)BATCH * ZDIM + (size_t)colv * ZDIM + ks * 32 + ((lane >> 4) << 3));
  }

  f32x4 a16[16], a8[8];
  f16x8 af[8], af4[4];
  zacc<16>(a16); gemm_regA<4, 16>(zp, pk + PK_G1, lane, a16);
  store_relu<16>(a16, g1b, B256, 264, lane); ldsfence();
  load_af<8>(B256, 264, lane, af); ldsfence();
  zacc<8>(a8); gemm_regA<8, 8>(af, pk + PK_G2, lane, a8);
  f32x4 gate[8];
#pragma unroll
  for (int j = 0; j < 8; ++j)
#pragma unroll
    for (int r = 0; r < 4; ++r)
      gate[j][r] = 1.f / (1.f + expf(-(a8[j][r] + g2b[j * 16 + colv])));
  zacc<16>(a16); gemm_regA<4, 16>(zp, pk + PK_P1, lane, a16);
  store_relu<16>(a16, p1b, B256, 264, lane); ldsfence();
  load_af<8>(B256, 264, lane, af); ldsfence();
  zacc<8>(a8); gemm_regA<8, 8>(af, pk + PK_P2, lane, a8);
  f32x4 prop[8];
#pragma unroll
  for (int j = 0; j < 8; ++j)
#pragma unroll
    for (int r = 0; r < 4; ++r) {
      float v = a8[j][r] + p2b[j * 16 + colv];
      prop[j][r] = v;
      B128[(rb + r) * 136 + j * 16 + colv] = (f16)fmaxf(v, 0.f);
    }
  ldsfence();
  zacc<8>(a8); gemm_regA<4, 8>(zp, pk + PK_TMU, lane, a8);
  f32x4 prmu[8];
#pragma unroll
  for (int j = 0; j < 8; ++j)
#pragma unroll
    for (int r = 0; r < 4; ++r) {
      float gg = gate[j][r];
      prmu[j][r] = (1.f - gg) * (a8[j][r] + tmub[j * 16 + colv]) + gg * prop[j][r];
    }
  load_af<4>(B128, 136, lane, af4); ldsfence();
  zacc<8>(a8); gemm_regA<4, 8>(af4, pk + PK_TLV, lane, a8);
  f32x4 prlv[8];
#pragma unroll
  for (int j = 0; j < 8; ++j)
#pragma unroll
    for (int r = 0; r < 4; ++r) prlv[j][r] = a8[j][r] + tlvb[j * 16 + colv];
  zacc<16>(a16); gemm_regA<4, 16>(zt, pk + PK_E1, lane, a16);
  store_relu<16>(a16, e1b, B256, 264, lane); ldsfence();
  load_af<8>(B256, 264, lane, af); ldsfence();
  zacc<16>(a16); gemm_regA<8, 16>(af, pk + PK_E2, lane, a16);
  store_relu<16>(a16, e2b, B256, 264, lane); ldsfence();
  load_af<8>(B256, 264, lane, af); ldsfence();
  zacc<8>(a8); gemm_regA<8, 8>(af, pk + PK_EMU, lane, a8);
  float srec = 0.f, skl = 0.f;
#pragma unroll
  for (int j = 0; j < 8; ++j)
#pragma unroll
    for (int r = 0; r < 4; ++r) {
      int row = rb + r, n = j * 16 + colv;
      size_t tb = (size_t)t * BATCH + b0 + row;
      float xt = a8[j][r] + emub[n] + eps_emit[tb * DIMX + n] * expf(0.5f * em_logvar[n]);
      float dy = xt - y[((size_t)(b0 + row) * T_LEN + t) * DIMX + n];
      srec += dy * dy;
      float m_ = (float)mu_all[tb * ZDIM + n], l_ = (float)lv_all[tb * ZDIM + n];
      float dm = m_ - prmu[j][r];
      skl += 0.5f * (prlv[j][r] - l_ + (expf(l_) + dm * dm) * expf(-prlv[j][r]) - 1.f);
    }
#pragma unroll
  for (int off = 32; off; off >>= 1) {
    srec += __shfl_xor(srec, off);
    skl += __shfl_xor(skl, off);
  }
  if (lane == 0) { wsum[w][0] = srec; wsum[w][1] = skl; }
  __syncthreads();
  if (tid == 0) {
    partials[blockIdx.x * 2 + 0] = wsum[0][0] + wsum[1][0] + wsum[2][0] + wsum[3][0];
    partials[blockIdx.x * 2 + 1] = wsum[0][1] + wsum[1][1] + wsum[2][1] + wsum[3][1];
  }
}

// =====================================================================
__global__ void finalize_kernel(const float* __restrict__ partials, float* __restrict__ out) {
  __shared__ float sm[256][2];
  int tid = threadIdx.x;
  float r = 0.f, kk = 0.f;
  for (int i = tid; i < 2048; i += 256) {
    r += partials[2 * i];
    kk += partials[2 * i + 1];
  }
  sm[tid][0] = r; sm[tid][1] = kk;
  __syncthreads();
  for (int off = 128; off; off >>= 1) {
    if (tid < off) { sm[tid][0] += sm[tid + off][0]; sm[tid][1] += sm[tid + off][1]; }
    __syncthreads();
  }
  if (tid == 0) {
    out[0] = sm[0][0] / (131072.f * 128.f);
    out[1] = sm[0][1] / 131072.f;
  }
}

// =====================================================================
extern "C" void kernel_launch(void* const* d_in, const int* in_sizes, int n_in,
                              void* d_out, int out_size, void* d_ws, size_t ws_size,
                              hipStream_t stream) {
  (void)in_sizes; (void)n_in; (void)out_size;
  const float* x        = (const float*)d_in[0];
  const float* y        = (const float*)d_in[1];
  const float* eps_comb = (const float*)d_in[2];
  const float* eps_emit = (const float*)d_in[3];
  const float* wih = (const float*)d_in[4];
  const float* whh = (const float*)d_in[5];
  const float* bih = (const float*)d_in[6];
  const float* bhh = (const float*)d_in[7];
  const float* h0  = (const float*)d_in[8];
  const float* zq0 = (const float*)d_in[9];
  const float* g1W = (const float*)d_in[10]; const float* g1b = (const float*)d_in[11];
  const float* g2W = (const float*)d_in[12]; const float* g2b = (const float*)d_in[13];
  const float* p1W = (const float*)d_in[14]; const float* p1b = (const float*)d_in[15];
  const float* p2W = (const float*)d_in[16]; const float* p2b = (const float*)d_in[17];
  const float* tmuW = (const float*)d_in[18]; const float* tmub = (const float*)d_in[19];
  const float* tlvW = (const float*)d_in[20]; const float* tlvb = (const float*)d_in[21];
  const float* chW = (const float*)d_in[22]; const float* chb = (const float*)d_in[23];
  const float* cmW = (const float*)d_in[24]; const float* cmb = (const float*)d_in[25];
  const float* clW = (const float*)d_in[26]; const float* clb = (const float*)d_in[27];
  const float* e1W = (const float*)d_in[28]; const float* e1b = (const float*)d_in[29];
  const float* e2W = (const float*)d_in[30]; const float* e2b = (const float*)d_in[31];
  const float* emW = (const float*)d_in[32]; const float* emb = (const float*)d_in[33];
  const float* elv = (const float*)d_in[34];

  char* ws = (char*)d_ws;
  f16*  xw      = (f16*)(ws + WS_XW);
  f16*  z_all   = (f16*)(ws + WS_Z);
  f16*  mu_all  = (f16*)(ws + WS_MU);
  f16*  lv_all  = (f16*)(ws + WS_LV);
  f16*  pk      = (f16*)(ws + WS_PK);
  float* partials = (float*)(ws + WS_PART);
  float* out = (float*)d_out;
  if (ws_size < WS_END) return;

#define PACK(S1, S2, NS_, K, N, OFF) \
  pack_kernel<<<dim3(((K) * (N)) / 256), dim3(256), 0, stream>>>(S1, S2, NS_, K, N, pk + (OFF))
  PACK(wih, wih, 512, 128, 512, PK_WIH);
  PACK(whh, whh, 512, 512, 512, PK_WHH);
  PACK(g1W, g1W, 256, 128, 256, PK_G1);
  PACK(g2W, g2W, 128, 256, 128, PK_G2);
  PACK(p1W, p1W, 256, 128, 256, PK_P1);
  PACK(p2W, p2W, 128, 256, 128, PK_P2);
  PACK(tmuW, tmuW, 128, 128, 128, PK_TMU);
  PACK(tlvW, tlvW, 128, 128, 128, PK_TLV);
  PACK(chW, chW, 512, 128, 512, PK_CBH);
  PACK(cmW, clW, 128, 512, 256, PK_CBML);
  PACK(e1W, e1W, 256, 128, 256, PK_E1);
  PACK(e2W, e2W, 256, 256, 256, PK_E2);
  PACK(emW, emW, 128, 256, 128, PK_EMU);
#undef PACK

  xw_kernel<<<dim3(2048), dim3(256), 0, stream>>>(x, pk, bih, bhh, xw);
  rnn_kernel<<<dim3(16), dim3(512), 0, stream>>>(pk, h0, xw);
  zscan_kernel<<<dim3(16), dim3(512), 0, stream>>>(pk, xw, chb, cmb, clb, zq0,
                                                   eps_comb, z_all, mu_all, lv_all);
  dpar_kernel<<<dim3(2048), dim3(256), 0, stream>>>(z_all, mu_all, lv_all, y, eps_emit, pk,
                                                    g1b, g2b, p1b, p2b, tmub, tlvb, e1b, e2b,
                                                    emb, elv, partials);
  finalize_kernel<<<dim3(1), dim3(256), 0, stream>>>(partials, out);
}